// Round 8
// baseline (632.905 us; speedup 1.0000x reference)
//
#include <hip/hip_runtime.h>
#include <stdint.h>

#define IN_F   4096
#define OUT_F  4096
#define M_TOT  8192   // 4 * 2048
#define BK     64
#define NT2    (IN_F / BK)   // 64 K-tiles
#define ABUF   32768         // A half of one dbuf (2 ks sub-blocks of 16 KiB)
#define HBUF   65536         // one dbuf: A 32K + B 32K  (2 bufs = 128 KiB)

typedef __bf16 bf16x8 __attribute__((ext_vector_type(8)));
typedef float  floatx4 __attribute__((ext_vector_type(4)));

// drain own LDS ops (ds_write visibility + ds_read completion) before barrier
#define LG() do {                                      \
    asm volatile("s_waitcnt lgkmcnt(0)" ::: "memory"); \
    __builtin_amdgcn_sched_barrier(0);                 \
} while (0)
// raw barrier WITHOUT the compiler's implicit vmcnt(0) drain (keeps the
// 2-tiles-ahead global loads in flight across tile boundaries)
#define FB() do {                                     \
    asm volatile("" ::: "memory");                    \
    __builtin_amdgcn_s_barrier();                     \
    asm volatile("" ::: "memory");                    \
    __builtin_amdgcn_sched_barrier(0);                \
} while (0)

__device__ __forceinline__ unsigned short f2bf_bits(float f) {
    union { float f; uint32_t u; } v; v.f = f;
    uint32_t r = v.u + 0x7FFF + ((v.u >> 16) & 1);   // RNE
    return (unsigned short)(r >> 16);
}

// one int32 (one byte of two 4-bit codes) -> two bf16 packed in a uint
__device__ __forceinline__ unsigned int pack2(int v, float s, float o) {
    unsigned int w0 = f2bf_bits((float)(v & 0xF) * s + o);
    unsigned int w1 = f2bf_bits((float)((v >> 4) & 0xF) * s + o);
    return w0 | (w1 << 16);
}

// ---- FUSED: C[M_TOT][OUT_F] = cvt_bf16(X) * dequant(P,S,O)^T + bias ----
// 256x256 tile, BK=64, 512 thr (2Mx4N waves, 128x64/wave, 8x4 MFMA 16x16x32).
// Staging is reg-based (global->reg->cvt/dequant->ds_write): x fp32 and packed
// int4 are consumed DIRECTLY (no converter kernels, no 96MB HBM round-trip).
// LDS layout identical to R6 (per-ks sub-blocks [256 rows][64 B], XOR swizzle
// byte_col ^= ((row>>1)&3)<<4; zero conflicts measured) so the read side +
// MFMA order are bit-identical to the R6-verified kernel.
// Pipeline per tile t: CVTWRITE(t+1 -> other dbuf) | 24 ds_read + 64 MFMA on
// tile t | ISSUE global loads(t+2) | lgkmcnt(0) + raw barrier. Loads are 2
// tiles ahead (compiler inserts precise vmcnt before the cvt uses them);
// ONE barrier per K-tile. Write/read target disjoint dbuf halves; barrier at
// end of t-1 guarantees buf[(t+1)&1]'s old readers are done (ledger sound).
// Audit (R7->R8): barrier-uniform control flow; LDS writes/reads bounded by
// HBUF*2; global reads bounded; no host API in kernel_launch.
__launch_bounds__(512, 2)
__global__ void gemm_fused_kernel(const float* __restrict__ X,    // [M_TOT][IN_F] fp32
                                  const int*   __restrict__ P,    // packed int4 [OUT_F*IN_F/2]
                                  const float* __restrict__ S,    // scales [groups]
                                  const float* __restrict__ Ofs,  // offsets [groups]
                                  const float* __restrict__ bias,
                                  float* __restrict__ C) {
    __shared__ __align__(16) char smem[2 * HBUF];   // 131072 B static LDS

    const int tid  = threadIdx.x;
    const int wave = tid >> 6;
    const int lane = tid & 63;
    const int quad = lane >> 4;
    const int l16  = lane & 15;
    const int wm   = wave >> 2;      // 0..1  (M)
    const int wn   = wave & 3;       // 0..3  (N)

    // XCD-chunked swizzle (bijective: 512 wgs, 8 XCDs, 64 wg/chunk)
    int id = blockIdx.y * gridDim.x + blockIdx.x;
    id = (id & 7) * 64 + (id >> 3);
    const int bn = id & 15;          // OUT_F/256 = 16
    const int bm = id >> 4;          // M_TOT/256 = 32

    // ---- A staging: 8 loads/tile; load j: row a_r0+j*32, fp32 cols [a_c4,+4)
    // within [K0,K0+64). Per instr: 4 rows x 256B contiguous (coalesced).
    const int a_r0 = tid >> 4;                 // 0..31
    const int a_c4 = (tid & 15) << 2;          // fp32 col 0..60
    const float* gx = X + (size_t)(bm * 256 + a_r0) * IN_F + a_c4;
    const int a_ks = a_c4 >> 5;                // K-half sub-block
    // swz(row) = ((row>>1)&3)<<4 is invariant under row+=32 -> fold into a_bc
    const int a_bc = ((a_c4 & 31) << 1) ^ (((a_r0 >> 1) & 3) << 4);  // byte col

    // ---- B staging: 4 loads/tile; load j: out-row b_r0+j*64, 4 int32 (8 codes)
    // at int offset b_i4 within row's [K0/2,+32). Per instr: 8 rows x 128B.
    const int b_r0 = tid >> 3;                 // 0..63
    const int b_i4 = (tid & 7) << 2;           // int32 offset 0..28
    const int* gp = P + (size_t)(bn * 256 + b_r0) * (IN_F / 2) + b_i4;
    const int b_ks = (tid & 7) >> 2;
    const int b_bc = (((tid & 7) & 3) << 4) ^ (((b_r0 >> 1) & 3) << 4);
    const int b_g0 = (bn * 256 + b_r0) * 32;   // group base; + j*2048 + (t>>1)

    float4 sA[8]; int4 sB[4]; float sS[4], sO[4];

    auto ISSUE = [&](int t) {
        const int K0 = t * BK;
#pragma unroll
        for (int j = 0; j < 8; ++j)
            sA[j] = *reinterpret_cast<const float4*>(gx + K0 + (size_t)j * 32 * IN_F);
#pragma unroll
        for (int j = 0; j < 4; ++j)
            sB[j] = *reinterpret_cast<const int4*>(gp + K0 / 2 + (size_t)j * 64 * (IN_F / 2));
#pragma unroll
        for (int j = 0; j < 4; ++j) {
            sS[j] = S[b_g0 + j * 2048 + (t >> 1)];
            sO[j] = Ofs[b_g0 + j * 2048 + (t >> 1)];
        }
    };

    auto CVTWRITE = [&](char* buf) {
        char* Ab = buf + a_ks * 16384;
#pragma unroll
        for (int j = 0; j < 8; ++j) {
            const int rj = a_r0 + j * 32;
            uint2 w;
            w.x = (unsigned)f2bf_bits(sA[j].x) | ((unsigned)f2bf_bits(sA[j].y) << 16);
            w.y = (unsigned)f2bf_bits(sA[j].z) | ((unsigned)f2bf_bits(sA[j].w) << 16);
            *reinterpret_cast<uint2*>(Ab + rj * 64 + a_bc) = w;
        }
        char* Bb = buf + ABUF + b_ks * 16384;
#pragma unroll
        for (int j = 0; j < 4; ++j) {
            const int rj = b_r0 + j * 64;
            uint4 w;
            w.x = pack2(sB[j].x, sS[j], sO[j]);
            w.y = pack2(sB[j].y, sS[j], sO[j]);
            w.z = pack2(sB[j].z, sS[j], sO[j]);
            w.w = pack2(sB[j].w, sS[j], sO[j]);
            *reinterpret_cast<uint4*>(Bb + rj * 64 + b_bc) = w;
        }
    };

    // ---- read side (identical to R6; swz invariant under row+16) ----
    const int arow0 = wm * 128 + l16;
    const int brow0 = wn * 64 + l16;
    const int acol = (((quad << 4) ^ (((arow0 >> 1) & 3) << 4)) >> 1);
    const int bcol = (((quad << 4) ^ (((brow0 >> 1) & 3) << 4)) >> 1);

    floatx4 acc[8][4] = {};
    bf16x8 a4[4], bb[4];

    auto RDA = [&](const ushort* bufp, int ks, int mh) {
#pragma unroll
        for (int mi = 0; mi < 4; ++mi)
            a4[mi] = *reinterpret_cast<const bf16x8*>(
                bufp + ks * 8192 + (arow0 + (mh * 4 + mi) * 16) * 32 + acol);
    };
    auto RDB = [&](const ushort* bufp, int ks) {
#pragma unroll
        for (int ni = 0; ni < 4; ++ni)
            bb[ni] = *reinterpret_cast<const bf16x8*>(
                bufp + 16384 + ks * 8192 + (brow0 + ni * 16) * 32 + bcol);
    };

#define MFMA16(MH) do {                                              \
    __builtin_amdgcn_s_setprio(1);                                   \
    _Pragma("unroll")                                                \
    for (int mi = 0; mi < 4; ++mi)                                   \
        _Pragma("unroll")                                            \
        for (int ni = 0; ni < 4; ++ni)                               \
            acc[(MH) * 4 + mi][ni] =                                 \
                __builtin_amdgcn_mfma_f32_16x16x32_bf16(             \
                    a4[mi], bb[ni], acc[(MH) * 4 + mi][ni], 0, 0, 0);\
    __builtin_amdgcn_s_setprio(0);                                   \
} while (0)

    // ---- prologue ----
    ISSUE(0);
    CVTWRITE(smem);          // tile 0 -> buf0 (auto vmcnt wait on sA/sB)
    ISSUE(1);
    LG(); FB();

    // ---- main loop: one barrier per K-tile ----
#pragma unroll 1
    for (int t = 0; t < NT2; ++t) {
        if (t + 1 < NT2) CVTWRITE(smem + ((t + 1) & 1) * HBUF);
        const ushort* bufp = (const ushort*)(smem + (t & 1) * HBUF);
        RDB(bufp, 0); RDA(bufp, 0, 0); MFMA16(0);
        RDA(bufp, 0, 1); MFMA16(1);
        if (t + 2 < NT2) ISSUE(t + 2);
        RDB(bufp, 1); RDA(bufp, 1, 0); MFMA16(0);
        RDA(bufp, 1, 1); MFMA16(1);
        LG(); FB();
    }
#undef MFMA16

    // ---- epilogue: D lane map col=l16, row=quad*4+r ----
    const int ccol = bn * 256 + wn * 64 + l16;
    const float* bp = bias + ccol;
    float* Cp = C + (size_t)(bm * 256 + wm * 128 + quad * 4) * OUT_F + ccol;
#pragma unroll
    for (int mi = 0; mi < 8; ++mi) {
#pragma unroll
        for (int ni = 0; ni < 4; ++ni) {
            float bv = bp[ni * 16];
#pragma unroll
            for (int r = 0; r < 4; ++r)
                Cp[(size_t)(mi * 16 + r) * OUT_F + ni * 16] = acc[mi][ni][r] + bv;
        }
    }
}

extern "C" void kernel_launch(void* const* d_in, const int* in_sizes, int n_in,
                              void* d_out, int out_size, void* d_ws, size_t ws_size,
                              hipStream_t stream) {
    const float* x       = (const float*)d_in[0];
    const int*   packed  = (const int*)d_in[1];
    const float* scales  = (const float*)d_in[2];
    const float* offsets = (const float*)d_in[3];
    const float* bias    = (const float*)d_in[4];
    float* out = (float*)d_out;

    dim3 grid(OUT_F / 256, M_TOT / 256);   // (16, 32) = 512 wgs
    gemm_fused_kernel<<<grid, 512, 0, stream>>>(x, packed, scales, offsets, bias, out);
}